// Round 6
// baseline (221.146 us; speedup 1.0000x reference)
//
#include <hip/hip_runtime.h>
#include <hip/hip_bf16.h>
#include <stdint.h>

typedef short bf16x8 __attribute__((ext_vector_type(8)));
typedef float f32x4 __attribute__((ext_vector_type(4)));
typedef unsigned short u16;

// ---- helpers -------------------------------------------------------------

__device__ __forceinline__ u16 f2bf_bits(float f) {
    __hip_bfloat16 h = __float2bfloat16(f);
    return __builtin_bit_cast(u16, h);
}

// pack two floats to bf16 pair (round-half-up): low = a, high = b
__device__ __forceinline__ uint32_t pack2bf(float a, float b) {
    uint32_t ua = __builtin_bit_cast(uint32_t, a) + 0x8000u;
    uint32_t ub = __builtin_bit_cast(uint32_t, b) + 0x8000u;
    return __builtin_amdgcn_perm(ub, ua, 0x07060302u);
}

// async global->LDS, 16B per lane; LDS dest = wave-uniform base + lane*16
__device__ __forceinline__ void gld_lds16(const void* g, void* l) {
    __builtin_amdgcn_global_load_lds(
        (const __attribute__((address_space(1))) void*)g,
        (__attribute__((address_space(3))) void*)l, 16, 0, 0);
}

#define CEXP 0.18033688011112042f  // log2(e)/8, folded into w_q/b_q at cast

// ---- fused cast kernel ---------------------------------------------------

__global__ __launch_bounds__(256) void cast_all_kernel(
    const float* __restrict__ x, const float* __restrict__ w0,
    const float* __restrict__ w1, const float* __restrict__ w2,
    const float* __restrict__ w3, u16* __restrict__ xb,
    u16* __restrict__ o0, u16* __restrict__ o1,
    u16* __restrict__ o2, u16* __restrict__ o3,
    const float* __restrict__ bq, const float* __restrict__ bk,
    const float* __restrict__ bv, float* __restrict__ biasf) {
    int gid = blockIdx.x * 256 + threadIdx.x;
    const float* s;
    u16* d;
    int off;
    float mul = 1.0f;
    if (gid < 1572864) {
        s = x; d = xb; off = gid;
    } else {
        int g2 = gid - 1572864;
        int which = g2 / 147456;
        off = g2 - which * 147456;
        s = which == 0 ? w0 : which == 1 ? w1 : which == 2 ? w2 : w3;
        d = which == 0 ? o0 : which == 1 ? o1 : which == 2 ? o2 : o3;
        if (which == 0) mul = CEXP;
    }
    float4 v = ((const float4*)s)[off];
    ushort4 u;
    u.x = f2bf_bits(v.x * mul); u.y = f2bf_bits(v.y * mul);
    u.z = f2bf_bits(v.z * mul); u.w = f2bf_bits(v.w * mul);
    ((ushort4*)d)[off] = u;
    if (gid < 2304) {
        float bb = gid < 768 ? bq[gid] * CEXP
                             : gid < 1536 ? bk[gid - 768] : bv[gid - 1536];
        biasf[gid] = bb;
    }
}

// ---- GEMM: C[m,n] = sum_k X[m,k]*W[n,k] + bias[n]  (both row-major in K)
// BK=64, block tile RT x 128, 4 waves 2x2, wave tile (RT/2) x 64.
// Double-buffered LDS (offset arithmetic, no LDS pointer arrays); prefetch
// kt+1 issued before compute(kt).
// MODE: 0 = bf16 out, 1 = f32 out, 2 = QKV fused (V n-tiles -> Vt transposed)

template <int RT, int MODE, int MINW>
__global__ __launch_bounds__(256, MINW) void gemm_xwt(
    const u16* __restrict__ X, const u16* __restrict__ W,
    const float* __restrict__ bias, float* __restrict__ Cf,
    u16* __restrict__ Cb, u16* __restrict__ Vt, int K, int NC) {
    constexpr int JR = RT / 32;
    constexpr int XSZ = RT * 64;       // one X buffer (u16 elems)
    constexpr int WSZ = 128 * 64;      // one W buffer
    __shared__ u16 pool[2 * XSZ + 2 * WSZ];
    const int tid = threadIdx.x;
    const int w = tid >> 6, lane = tid & 63;
    const int quad = lane >> 4, l15 = lane & 15;
    const int m0 = blockIdx.y * RT, n0 = blockIdx.x * 128;
    const int wr = (w >> 1) * (RT / 2), wc = (w & 1) * 64;
    const int rr = lane >> 3, c8 = lane & 7;

    auto stage = [&](int kt, int pb) {
        const int k0 = kt * 64;
        u16* bx = pool + pb * XSZ;
        u16* bw = pool + 2 * XSZ + pb * WSZ;
        for (int cb = w; cb < RT / 8; cb += 4) {
            int row = cb * 8 + rr;
            int cg = c8 ^ ((rr ^ cb) & 7);
            gld_lds16(X + (size_t)(m0 + row) * K + k0 + cg * 8, &bx[cb * 512]);
        }
        for (int cb = w; cb < 16; cb += 4) {
            int row = cb * 8 + rr;
            int cg = c8 ^ ((rr ^ cb) & 7);
            gld_lds16(W + (size_t)(n0 + row) * K + k0 + cg * 8, &bw[cb * 512]);
        }
    };

    f32x4 acc[JR][4];
    for (int j = 0; j < JR; ++j)
        for (int i = 0; i < 4; ++i) acc[j][i] = (f32x4){0.f, 0.f, 0.f, 0.f};

    const int KT = K / 64;
    stage(0, 0);
    __syncthreads();
    for (int kt = 0; kt < KT; ++kt) {
        const int pb = kt & 1;
        if (kt + 1 < KT) stage(kt + 1, pb ^ 1);
        const u16* bx = pool + pb * XSZ;
        const u16* bw = pool + 2 * XSZ + pb * WSZ;
        for (int kk = 0; kk < 2; ++kk) {
            bf16x8 xf[JR], wf[4];
            for (int j = 0; j < JR; ++j) {
                int row = wr + j * 16 + l15;
                int slot = (kk * 4 + quad) ^ ((row ^ (row >> 3)) & 7);
                xf[j] = *(const bf16x8*)&bx[row * 64 + slot * 8];
            }
            for (int i = 0; i < 4; ++i) {
                int row = wc + i * 16 + l15;
                int slot = (kk * 4 + quad) ^ ((row ^ (row >> 3)) & 7);
                wf[i] = *(const bf16x8*)&bw[row * 64 + slot * 8];
            }
            for (int j = 0; j < JR; ++j)
                for (int i = 0; i < 4; ++i)
                    acc[j][i] = __builtin_amdgcn_mfma_f32_16x16x32_bf16(
                        wf[i], xf[j], acc[j][i], 0, 0, 0);
        }
        __syncthreads();
    }

    const bool vtile = (MODE == 2) && (n0 >= 1536);
    if (vtile) {
        // V tile: round-trip through LDS (pool is free after last barrier)
        // T2[n_local][m_local], row stride 136 u16.
        u16* T2 = pool;
        for (int i = 0; i < 4; ++i) {
            int nl = wc + i * 16 + quad * 4;
            int c0 = n0 + nl;
            float4 bv4 = *(const float4*)&bias[c0];
            for (int j = 0; j < JR; ++j) {
                int ml = wr + j * 16 + l15;
                T2[(nl + 0) * 136 + ml] = f2bf_bits(acc[j][i][0] + bv4.x);
                T2[(nl + 1) * 136 + ml] = f2bf_bits(acc[j][i][1] + bv4.y);
                T2[(nl + 2) * 136 + ml] = f2bf_bits(acc[j][i][2] + bv4.z);
                T2[(nl + 3) * 136 + ml] = f2bf_bits(acc[j][i][3] + bv4.w);
            }
        }
        __syncthreads();
        int sc = (tid & 15) * 8;
        int bq_ = m0 >> 11;          // batch index
        int s0 = m0 & 2047;          // sequence position within batch (BUG FIX)
        for (int rnd = 0; rnd < 8; ++rnd) {
            int dl = (tid >> 4) + rnd * 16;
            bf16x8 vv = *(const bf16x8*)&T2[dl * 136 + sc];
            int dg = n0 + dl - 1536;
            int h = dg >> 6, dd = dg & 63;
            *(bf16x8*)&Vt[((size_t)(bq_ * 12 + h) * 64 + dd) * 2048 + s0 + sc] = vv;
        }
    } else {
        for (int i = 0; i < 4; ++i) {
            int c0 = n0 + wc + i * 16 + quad * 4;
            float4 bv4 = *(const float4*)&bias[c0];
            for (int j = 0; j < JR; ++j) {
                int row = m0 + wr + j * 16 + l15;
                float v0 = acc[j][i][0] + bv4.x;
                float v1 = acc[j][i][1] + bv4.y;
                float v2 = acc[j][i][2] + bv4.z;
                float v3 = acc[j][i][3] + bv4.w;
                if (MODE == 1) {
                    float4 o4 = {v0, v1, v2, v3};
                    *(float4*)&Cf[(size_t)row * NC + c0] = o4;
                } else {
                    uint2 pk = {pack2bf(v0, v1), pack2bf(v2, v3)};
                    *(uint2*)&Cb[(size_t)row * NC + c0] = pk;
                }
            }
        }
    }
}

// ---- flash attention, S^T form, fixed-max softmax, double-buffered K/V ---
// Block = (b,h, 128 q rows), 4 waves. Q staged once into buffer 1; after
// frags are hoisted, buffer 1 is reused for K/V. l row-sums come free from
// an extra ones-MFMA in the PV step (no VALU adds, no shuffles).

__global__ __launch_bounds__(256, 3) void attn_kernel(
    const u16* __restrict__ QKV, const u16* __restrict__ Vt, u16* __restrict__ O) {
    __shared__ u16 lsKV[2 * 128 * 64];   // buf0 | buf1 (buf1 doubles as Q stage)
    __shared__ u16 lsP[4][32 * 72];

    int bx = blockIdx.x;             // 768 = 48 * 16
    int bh = bx % 48;
    int qtb = 15 - (bx / 48);        // longest blocks dispatch first
    int b = bh / 12, h = bh % 12;
    int tid = threadIdx.x, w = tid >> 6, lane = tid & 63;
    int quad = lane >> 4, l15 = lane & 15;
    int rr = lane >> 3, c8 = lane & 7;

    auto stageKV = [&](int kt, int pb) {
        u16* dst = lsKV + pb * 8192;
        for (int cb = w; cb < 16; cb += 4) {
            int r = (cb & 7) * 8 + rr;
            int cg = c8 ^ ((rr ^ cb) & 7);
            const u16* g = (cb < 8)
                ? QKV + (size_t)(b * 2048 + kt * 64 + r) * 2304 + 768 + h * 64 + cg * 8
                : Vt + (size_t)(bh * 64 + r) * 2048 + kt * 64 + cg * 8;
            gld_lds16(g, &dst[cb * 512]);
        }
    };

    // stage Q (into buf1) and kt=0 K/V (into buf0)
    {
        u16* qs = lsKV + 8192;
        for (int cb = w; cb < 16; cb += 4) {
            int row = cb * 8 + rr;
            int cg = c8 ^ ((rr ^ cb) & 7);
            gld_lds16(QKV + (size_t)(b * 2048 + qtb * 128 + row) * 2304 + h * 64 + cg * 8,
                      &qs[cb * 512]);
        }
    }
    stageKV(0, 0);
    __syncthreads();

    bf16x8 q0[2], q1[2];
    for (int g = 0; g < 2; ++g) {
        const u16* qs = lsKV + 8192;
        int rowq = g * 64 + w * 16 + l15;
        int swq = (rowq ^ (rowq >> 3)) & 7;
        q0[g] = *(const bf16x8*)&qs[rowq * 64 + ((0 + quad) ^ swq) * 8];
        q1[g] = *(const bf16x8*)&qs[rowq * 64 + ((4 + quad) ^ swq) * 8];
    }
    __syncthreads();   // all waves done reading Q; buf1 free for K/V

    const bf16x8 ones = {(short)0x3F80, (short)0x3F80, (short)0x3F80, (short)0x3F80,
                         (short)0x3F80, (short)0x3F80, (short)0x3F80, (short)0x3F80};
    f32x4 oacc0[4], oacc1[4], lacc0, lacc1;
    for (int dt = 0; dt < 4; ++dt) {
        oacc0[dt] = (f32x4){0.f, 0.f, 0.f, 0.f};
        oacc1[dt] = (f32x4){0.f, 0.f, 0.f, 0.f};
    }
    lacc0 = (f32x4){0.f, 0.f, 0.f, 0.f};
    lacc1 = (f32x4){0.f, 0.f, 0.f, 0.f};
    u16* Pw = lsP[w];
    const int qrel = w * 16 + l15;
    const int ktmax = 2 * qtb + 1;

    for (int kt = 0; kt <= ktmax; ++kt) {
        const int pb = kt & 1;
        if (kt < ktmax) stageKV(kt + 1, pb ^ 1);
        const u16* Kf = lsKV + pb * 8192;
        const u16* Vf = Kf + 4096;
        const bool do0 = (kt <= 2 * qtb);

        f32x4 S0[4], S1[4];
        for (int ct = 0; ct < 4; ++ct) {
            int rowk = ct * 16 + l15;
            int swk = (rowk ^ (rowk >> 3)) & 7;
            bf16x8 k0 = *(const bf16x8*)&Kf[rowk * 64 + ((0 + quad) ^ swk) * 8];
            bf16x8 k1 = *(const bf16x8*)&Kf[rowk * 64 + ((4 + quad) ^ swk) * 8];
            f32x4 z = (f32x4){0.f, 0.f, 0.f, 0.f};
            S1[ct] = __builtin_amdgcn_mfma_f32_16x16x32_bf16(k0, q0[1], z, 0, 0, 0);
            S1[ct] = __builtin_amdgcn_mfma_f32_16x16x32_bf16(k1, q1[1], S1[ct], 0, 0, 0);
            if (do0) {
                S0[ct] = __builtin_amdgcn_mfma_f32_16x16x32_bf16(k0, q0[0], z, 0, 0, 0);
                S0[ct] = __builtin_amdgcn_mfma_f32_16x16x32_bf16(k1, q1[0], S0[ct], 0, 0, 0);
            }
        }

        if (kt == 2 * qtb) {
            for (int ct = 0; ct < 4; ++ct) {
                int kbase = ct * 16 + quad * 4;
                for (int r = 0; r < 4; ++r)
                    if (kbase + r > qrel) S0[ct][r] = -1e30f;
            }
        }
        if (kt == 2 * qtb + 1) {
            for (int ct = 0; ct < 4; ++ct) {
                int kbase = ct * 16 + quad * 4;
                for (int r = 0; r < 4; ++r)
                    if (kbase + r > qrel) S1[ct][r] = -1e30f;
            }
        }

        // p = exp2(s) (scale pre-folded into Q); store P rows (b64, padded)
        if (do0) {
            u16* Pr = &Pw[(size_t)l15 * 72];
            for (int ct = 0; ct < 4; ++ct) {
                float p0 = __builtin_amdgcn_exp2f(S0[ct][0]);
                float p1 = __builtin_amdgcn_exp2f(S0[ct][1]);
                float p2 = __builtin_amdgcn_exp2f(S0[ct][2]);
                float p3 = __builtin_amdgcn_exp2f(S0[ct][3]);
                uint2 pk = {pack2bf(p0, p1), pack2bf(p2, p3)};
                *(uint2*)&Pr[ct * 16 + quad * 4] = pk;
            }
        }
        {
            u16* Pr = &Pw[(size_t)(16 + l15) * 72];
            for (int ct = 0; ct < 4; ++ct) {
                float p0 = __builtin_amdgcn_exp2f(S1[ct][0]);
                float p1 = __builtin_amdgcn_exp2f(S1[ct][1]);
                float p2 = __builtin_amdgcn_exp2f(S1[ct][2]);
                float p3 = __builtin_amdgcn_exp2f(S1[ct][3]);
                uint2 pk = {pack2bf(p0, p1), pack2bf(p2, p3)};
                *(uint2*)&Pr[ct * 16 + quad * 4] = pk;
            }
        }
        // same-wave LDS RAW: DS pipe is in-order within a wave

        // O^T += V^T * P^T ; l = ones * P^T (free row-sum via MFMA)
        for (int ks = 0; ks < 2; ++ks) {
            bf16x8 bp1 = *(const bf16x8*)&Pw[(size_t)(16 + l15) * 72 + ks * 32 + quad * 8];
            bf16x8 bp0;
            if (do0) bp0 = *(const bf16x8*)&Pw[(size_t)l15 * 72 + ks * 32 + quad * 8];
            lacc1 = __builtin_amdgcn_mfma_f32_16x16x32_bf16(ones, bp1, lacc1, 0, 0, 0);
            if (do0)
                lacc0 = __builtin_amdgcn_mfma_f32_16x16x32_bf16(ones, bp0, lacc0, 0, 0, 0);
            for (int dt = 0; dt < 4; ++dt) {
                int rowv = dt * 16 + l15;
                int swv = (rowv ^ (rowv >> 3)) & 7;
                bf16x8 av = *(const bf16x8*)&Vf[rowv * 64 + ((ks * 4 + quad) ^ swv) * 8];
                oacc1[dt] = __builtin_amdgcn_mfma_f32_16x16x32_bf16(av, bp1, oacc1[dt], 0, 0, 0);
                if (do0)
                    oacc0[dt] = __builtin_amdgcn_mfma_f32_16x16x32_bf16(av, bp0, oacc0[dt], 0, 0, 0);
            }
        }
        __syncthreads();
    }

    float inv0 = 1.0f / lacc0[0], inv1 = 1.0f / lacc1[0];
    for (int g = 0; g < 2; ++g) {
        float inv = g ? inv1 : inv0;
        f32x4* oa = g ? oacc1 : oacc0;
        int row = qtb * 128 + g * 64 + w * 16 + l15;
        for (int dt = 0; dt < 4; ++dt) {
            uint2 pk = {pack2bf(oa[dt][0] * inv, oa[dt][1] * inv),
                        pack2bf(oa[dt][2] * inv, oa[dt][3] * inv)};
            *(uint2*)&O[(size_t)(b * 2048 + row) * 768 + h * 64 + dt * 16 + quad * 4] = pk;
        }
    }
}

// ---- launch --------------------------------------------------------------

extern "C" void kernel_launch(void* const* d_in, const int* in_sizes, int n_in,
                              void* d_out, int out_size, void* d_ws, size_t ws_size,
                              hipStream_t stream) {
    const float* x  = (const float*)d_in[0];
    const float* wq = (const float*)d_in[1];
    const float* bq = (const float*)d_in[2];
    const float* wk = (const float*)d_in[3];
    const float* bk = (const float*)d_in[4];
    const float* wv = (const float*)d_in[5];
    const float* bv = (const float*)d_in[6];
    const float* wo = (const float*)d_in[7];
    const float* bo = (const float*)d_in[8];
    float* out = (float*)d_out;

    char* ws = (char*)d_ws;
    u16*   xb    = (u16*)(ws + 0);            // 8192x768 bf16
    u16*   Wf    = (u16*)(ws + 12582912);     // 2304x768 bf16 (wq pre-scaled)
    u16*   wob   = (u16*)(ws + 16121856);     //  768x768 bf16
    float* biasf = (float*)(ws + 17301504);   // 2304 f32
    u16*   QKVb  = (u16*)(ws + 17310720);     // 8192x2304 bf16 (V region unused)
    u16*   Vtw   = (u16*)(ws + 55059456);     // 48x64x2048 bf16
    u16*   Ow    = (u16*)(ws + 67642368);     // 8192x768 bf16

    cast_all_kernel<<<8448, 256, 0, stream>>>(x, wq, wk, wv, wo,
                                              xb, Wf, Wf + 589824, Wf + 1179648, wob,
                                              bq, bk, bv, biasf);

    // fused QKV projection (V tiles stored transposed into Vtw)
    gemm_xwt<128, 2, 2><<<dim3(18, 64), 256, 0, stream>>>(xb, Wf, biasf, nullptr,
                                                          QKVb, Vtw, 768, 2304);
    attn_kernel<<<768, 256, 0, stream>>>(QKVb, Vtw, Ow);
    // output projection -> fp32 d_out
    gemm_xwt<64, 1, 3><<<dim3(6, 128), 256, 0, stream>>>(Ow, wob, bo, out, nullptr,
                                                         nullptr, 768, 768);
}